// Round 2
// baseline (21555.864 us; speedup 1.0000x reference)
//
#include <hip/hip_runtime.h>
#include <hip/hip_bf16.h>
#include <math.h>

#define SZ    300     // SIZE
#define TS    64
#define B_    512     // batch
#define NS    128     // N stack/buffer slots
#define TT    255     // T = 2N-1
#define G4    256     // 4*TS
#define R5    1500    // 5*SIZE

__device__ __forceinline__ float sigf(float x) { return 1.f / (1.f + expf(-x)); }

// ---------------------------------------------------------------------------
// Setup: zero the per-step reduce counters (ws is poisoned before each call).
// ---------------------------------------------------------------------------
__global__ void kZero(int* __restrict__ nred)
{
    int i = threadIdx.x;
    if (i < TT) nred[i] = 0;
}

// ---------------------------------------------------------------------------
// Pointer schedule is data-independent. One thread per batch row simulates
// the stack: start-of-step sptr/bptr, source indirection for s1/s2 slots
// (token index >=0, or -1 meaning "materialized reduce output in stack"),
// per-step reduce row lists, final-output source. Also zeroes th/tc/nll.
// ---------------------------------------------------------------------------
__global__ void kSched(const int* __restrict__ trans, int* __restrict__ sptrA,
                       int* __restrict__ bptrA, int* __restrict__ s1src,
                       int* __restrict__ s2src, int* __restrict__ finSrc,
                       int* __restrict__ redList, int* __restrict__ nred,
                       float* __restrict__ th, float* __restrict__ tc,
                       float* __restrict__ nll_row)
{
    int b = blockIdx.x * blockDim.x + threadIdx.x;
    if (b >= B_) return;
    int srcArr[NS];            // per-slot source: token idx or -1 (reduce output)
    int sp = 0, bp = 0;
    for (int t = 0; t < TT; ++t) {
        sptrA[t * B_ + b] = sp;
        bptrA[t * B_ + b] = bp;
        s1src[t * B_ + b] = (sp >= 1) ? srcArr[sp - 1] : -1;
        s2src[t * B_ + b] = (sp >= 2) ? srcArr[sp - 2] : -1;
        int tr = trans[b * TT + t];
        if (tr) {
            int pos = atomicAdd(&nred[t], 1);
            redList[t * B_ + pos] = b;
            srcArr[sp - 2] = -1;     // slot becomes a materialized reduce output
            sp -= 1;
        } else {
            srcArr[sp] = min(bp, NS - 1);
            sp += 1; bp += 1;
        }
    }
    sptrA[TT * B_ + b] = sp;
    finSrc[b] = srcArr[max(sp - 1, 0)];
    for (int k = 0; k < TS; ++k) {
        th[(size_t)b * TS + k] = 0.f;
        tc[(size_t)b * TS + k] = 0.f;
    }
    nll_row[b] = 0.f;
}

// ---------------------------------------------------------------------------
// K1 (per step): blocks 0..383 compute rPart = s2h@WL + bL + s1h@WR for
// reduce rows only (12 col-chunks of 125  x  32 row-tile slots, tiles of 8
// rows from the compacted list). Blocks 384..511 compute
// x = bh@Wb + s1h@Ws1 + s2h@Ws2 for all rows (64 row-groups of 8 x 2
// col-halves of 128). Stack is fully up to date (K3 of step t-1 wrote
// reduce outputs in place; shifts are indirected to tokens).
// ---------------------------------------------------------------------------
__global__ __launch_bounds__(512) void kStep1(
    const float* __restrict__ tokens, const float* __restrict__ Wb,
    const float* __restrict__ Ws1, const float* __restrict__ Ws2,
    const float* __restrict__ WL, const float* __restrict__ WR,
    const float* __restrict__ bL, const float* __restrict__ stack,
    float* __restrict__ xBuf, float* __restrict__ rPart,
    const int* __restrict__ sptrA, const int* __restrict__ bptrA,
    const int* __restrict__ s1src, const int* __restrict__ s2src,
    const int* __restrict__ redList, const int* __restrict__ nred, int t)
{
    __shared__ __align__(16) float sm[8 * 912];
    const int tid = threadIdx.x;
    const int bid = blockIdx.x;

    if (bid < 384) {
        // ----- rPart for reduce rows -----
        const int chunk = bid % 12;           // 125-col chunk
        const int slot  = bid / 12;           // 0..31
        const int col0  = chunk * 125;
        const int nr    = nred[t];
        for (int tile = slot; tile * 8 < nr; tile += 32) {
            const int base = tile * 8;
            const int cnt  = min(8, nr - base);
            // gather s1h (offset 0) / s2h (offset 304) for up to 8 rows
            for (int r = 0; r < cnt; ++r) {
                int b  = redList[t * B_ + base + r];
                int sp = sptrA[t * B_ + b];       // reduce => sp >= 2
                int i1 = s1src[t * B_ + b], i2 = s2src[t * B_ + b];
                const float* p1 = (i1 >= 0) ? tokens + ((size_t)b * NS + i1) * 600
                                            : stack  + ((size_t)b * NS + sp - 1) * 600;
                const float* p2 = (i2 >= 0) ? tokens + ((size_t)b * NS + i2) * 600
                                            : stack  + ((size_t)b * NS + sp - 2) * 600;
                for (int i = tid; i < SZ; i += 512) {
                    sm[r * 608 + i]       = p1[i];
                    sm[r * 608 + 304 + i] = p2[i];
                }
            }
            __syncthreads();
            const int c = tid & 127;
            const int q = tid >> 7;            // rows 2q, 2q+1
            if (c < 125) {
                const int col = col0 + c;
                float a0 = bL[col], a1 = a0;
                const float* s0 = sm + (2 * q) * 608;
                const float* s1 = sm + (2 * q + 1) * 608;
                for (int k = 0; k < SZ; k += 4) {
                    float wr0 = WR[(size_t)(k + 0) * R5 + col];
                    float wr1 = WR[(size_t)(k + 1) * R5 + col];
                    float wr2 = WR[(size_t)(k + 2) * R5 + col];
                    float wr3 = WR[(size_t)(k + 3) * R5 + col];
                    float wl0 = WL[(size_t)(k + 0) * R5 + col];
                    float wl1 = WL[(size_t)(k + 1) * R5 + col];
                    float wl2 = WL[(size_t)(k + 2) * R5 + col];
                    float wl3 = WL[(size_t)(k + 3) * R5 + col];
                    float4 h10 = *(const float4*)&s0[k];
                    float4 h20 = *(const float4*)&s0[304 + k];
                    float4 h11 = *(const float4*)&s1[k];
                    float4 h21 = *(const float4*)&s1[304 + k];
                    a0 += h10.x * wr0 + h10.y * wr1 + h10.z * wr2 + h10.w * wr3
                        + h20.x * wl0 + h20.y * wl1 + h20.z * wl2 + h20.w * wl3;
                    a1 += h11.x * wr0 + h11.y * wr1 + h11.z * wr2 + h11.w * wr3
                        + h21.x * wl0 + h21.y * wl1 + h21.z * wl2 + h21.w * wl3;
                }
                int r0 = 2 * q, r1 = 2 * q + 1;
                if (r0 < cnt) {
                    int b = redList[t * B_ + base + r0];
                    rPart[(size_t)b * R5 + col] = a0;
                }
                if (r1 < cnt) {
                    int b = redList[t * B_ + base + r1];
                    rPart[(size_t)b * R5 + col] = a1;
                }
            }
            __syncthreads();
        }
    } else {
        // ----- x for all rows -----
        const int idx  = bid - 384;
        const int rg   = idx >> 1;            // 8-row group
        const int half = idx & 1;             // 128-col half
        const int b0   = rg * 8;
        for (int r = 0; r < 8; ++r) {
            int b  = b0 + r;
            int sp = sptrA[t * B_ + b];
            int bp = bptrA[t * B_ + b];
            int i1 = s1src[t * B_ + b], i2 = s2src[t * B_ + b];
            const float* pb = tokens + ((size_t)b * NS + min(bp, NS - 1)) * 600;
            const float* p1 = (i1 >= 0) ? tokens + ((size_t)b * NS + i1) * 600
                                        : stack  + ((size_t)b * NS + max(sp - 1, 0)) * 600;
            const float* p2 = (i2 >= 0) ? tokens + ((size_t)b * NS + i2) * 600
                                        : stack  + ((size_t)b * NS + max(sp - 2, 0)) * 600;
            bool z1 = sp < 1, z2 = sp < 2;
            for (int i = tid; i < SZ; i += 512) {
                sm[r * 912 + i]       = pb[i];
                sm[r * 912 + 304 + i] = z1 ? 0.f : p1[i];
                sm[r * 912 + 608 + i] = z2 ? 0.f : p2[i];
            }
        }
        __syncthreads();
        const int j   = tid & 127;
        const int q   = tid >> 7;             // rows 2q, 2q+1
        const int col = half * 128 + j;
        float a0 = 0.f, a1 = 0.f;
        const float* s0 = sm + (2 * q) * 912;
        const float* s1 = sm + (2 * q + 1) * 912;
        for (int k = 0; k < SZ; k += 4) {
            float wb0 = Wb [(size_t)(k + 0) * G4 + col];
            float wb1 = Wb [(size_t)(k + 1) * G4 + col];
            float wb2 = Wb [(size_t)(k + 2) * G4 + col];
            float wb3 = Wb [(size_t)(k + 3) * G4 + col];
            float w10 = Ws1[(size_t)(k + 0) * G4 + col];
            float w11 = Ws1[(size_t)(k + 1) * G4 + col];
            float w12 = Ws1[(size_t)(k + 2) * G4 + col];
            float w13 = Ws1[(size_t)(k + 3) * G4 + col];
            float w20 = Ws2[(size_t)(k + 0) * G4 + col];
            float w21 = Ws2[(size_t)(k + 1) * G4 + col];
            float w22 = Ws2[(size_t)(k + 2) * G4 + col];
            float w23 = Ws2[(size_t)(k + 3) * G4 + col];
            float4 vb0 = *(const float4*)&s0[k];
            float4 v10 = *(const float4*)&s0[304 + k];
            float4 v20 = *(const float4*)&s0[608 + k];
            float4 vb1 = *(const float4*)&s1[k];
            float4 v11 = *(const float4*)&s1[304 + k];
            float4 v21 = *(const float4*)&s1[608 + k];
            a0 += vb0.x * wb0 + vb0.y * wb1 + vb0.z * wb2 + vb0.w * wb3
                + v10.x * w10 + v10.y * w11 + v10.z * w12 + v10.w * w13
                + v20.x * w20 + v20.y * w21 + v20.z * w22 + v20.w * w23;
            a1 += vb1.x * wb0 + vb1.y * wb1 + vb1.z * wb2 + vb1.w * wb3
                + v11.x * w10 + v11.y * w11 + v11.z * w12 + v11.w * w13
                + v21.x * w20 + v21.y * w21 + v21.z * w22 + v21.w * w23;
        }
        xBuf[(size_t)(b0 + 2 * q) * G4 + col]     = a0;
        xBuf[(size_t)(b0 + 2 * q + 1) * G4 + col] = a1;
    }
}

// ---------------------------------------------------------------------------
// K2 (per step): g = x@W_ih + th@W_hh, tracking-LSTM pointwise (th/tc
// updated in place), logits -> per-row nll accumulation.
// 64 blocks x 8 rows, 512 threads.
// ---------------------------------------------------------------------------
__global__ __launch_bounds__(512) void kStep2(
    const float* __restrict__ W_ih, const float* __restrict__ W_hh,
    const float* __restrict__ Wt, const float* __restrict__ bt,
    const int* __restrict__ trans, const float* __restrict__ xBuf,
    float* __restrict__ th, float* __restrict__ tc,
    float* __restrict__ nll_row, int t)
{
    __shared__ __align__(16) float sX[8][G4];
    __shared__ __align__(16) float sTh[8][TS];
    __shared__ __align__(16) float sG[8][G4];
    __shared__ float sThn[8][TS];

    const int tid = threadIdx.x;
    const int b0  = blockIdx.x * 8;

    for (int i = tid; i < 8 * G4; i += 512) sX[i >> 8][i & 255] = xBuf[(size_t)b0 * G4 + i];
    for (int i = tid; i < 8 * TS; i += 512) sTh[i >> 6][i & 63] = th[(size_t)b0 * TS + i];
    __syncthreads();

    const int j = tid & 255;
    const int h = tid >> 8;                   // rows 4h..4h+3
    float a[4] = {0.f, 0.f, 0.f, 0.f};
    for (int k = 0; k < G4; k += 4) {
        float w0 = W_ih[(size_t)(k + 0) * G4 + j];
        float w1 = W_ih[(size_t)(k + 1) * G4 + j];
        float w2 = W_ih[(size_t)(k + 2) * G4 + j];
        float w3 = W_ih[(size_t)(k + 3) * G4 + j];
        #pragma unroll
        for (int r = 0; r < 4; ++r) {
            float4 vx = *(const float4*)&sX[4 * h + r][k];
            a[r] += vx.x * w0 + vx.y * w1 + vx.z * w2 + vx.w * w3;
        }
    }
    for (int k = 0; k < TS; k += 4) {
        float w0 = W_hh[(size_t)(k + 0) * G4 + j];
        float w1 = W_hh[(size_t)(k + 1) * G4 + j];
        float w2 = W_hh[(size_t)(k + 2) * G4 + j];
        float w3 = W_hh[(size_t)(k + 3) * G4 + j];
        #pragma unroll
        for (int r = 0; r < 4; ++r) {
            float4 vt = *(const float4*)&sTh[4 * h + r][k];
            a[r] += vt.x * w0 + vt.y * w1 + vt.z * w2 + vt.w * w3;
        }
    }
    #pragma unroll
    for (int r = 0; r < 4; ++r) sG[4 * h + r][j] = a[r];
    __syncthreads();

    // pointwise: 8 waves, wave r = row r, lane k
    const int r = tid >> 6, k = tid & 63;
    const int b = b0 + r;
    {
        float gi = sG[r][k], gf = sG[r][TS + k], gg = sG[r][2 * TS + k], go = sG[r][3 * TS + k];
        float tcv = tc[(size_t)b * TS + k];
        float tcn = sigf(gf) * tcv + sigf(gi) * tanhf(gg);
        float thn = sigf(go) * tanhf(tcn);
        tc[(size_t)b * TS + k] = tcn;
        th[(size_t)b * TS + k] = thn;
        sThn[r][k] = thn;
    }
    // logits via wave reduction (no extra sync needed: wave-local data)
    {
        float v  = sThn[r][k];
        float p0 = v * Wt[2 * k + 0];
        float p1 = v * Wt[2 * k + 1];
        #pragma unroll
        for (int o = 32; o > 0; o >>= 1) {
            p0 += __shfl_xor(p0, o, 64);
            p1 += __shfl_xor(p1, o, 64);
        }
        if (k == 0) {
            float l0 = p0 + bt[0], l1 = p1 + bt[1];
            float m = fmaxf(l0, l1);
            float lse = m + logf(expf(l0 - m) + expf(l1 - m));
            int tr = trans[b * TT + t];
            nll_row[b] += lse - (tr ? l1 : l0);
        }
    }
}

// ---------------------------------------------------------------------------
// K3 (per step): finish r for reduce rows: r = rPart + th_new@Wtr, tree-LSTM
// pointwise, write [rh|rc] DIRECTLY into stack slot sp-2.
// Grid: 300 blocks, block c owns tree-column c (gate cols c+300g). Writes of
// block c are cols {c, 300+c}; its only slot-reads are col 300+c of the same
// slot (same thread, read-before-write) -> race-free across blocks/threads.
// ---------------------------------------------------------------------------
__global__ __launch_bounds__(256) void kStep3(
    const float* __restrict__ tokens, const float* __restrict__ Wtr,
    const float* __restrict__ th, const float* __restrict__ rPart,
    float* __restrict__ stack, const int* __restrict__ sptrA,
    const int* __restrict__ s1src, const int* __restrict__ s2src,
    const int* __restrict__ redList, const int* __restrict__ nred, int t)
{
    __shared__ float sW[5][TS];
    const int tid = threadIdx.x;
    const int c   = blockIdx.x;               // tree-col 0..299
    for (int i = tid; i < 5 * TS; i += 256) {
        int g = i >> 6, k = i & 63;
        sW[g][k] = Wtr[(size_t)k * R5 + g * SZ + c];
    }
    __syncthreads();
    const int nr = nred[t];
    for (int jj = tid; jj < nr; jj += 256) {
        int b  = redList[t * B_ + jj];
        int sp = sptrA[t * B_ + b];           // >= 2 for reduce rows
        const float* thr = th + (size_t)b * TS;   // already th_new
        float a0 = 0.f, a1 = 0.f, a2 = 0.f, a3 = 0.f, a4 = 0.f;
        for (int k = 0; k < TS; k += 4) {
            float4 tv = *(const float4*)&thr[k];
            a0 += tv.x * sW[0][k] + tv.y * sW[0][k+1] + tv.z * sW[0][k+2] + tv.w * sW[0][k+3];
            a1 += tv.x * sW[1][k] + tv.y * sW[1][k+1] + tv.z * sW[1][k+2] + tv.w * sW[1][k+3];
            a2 += tv.x * sW[2][k] + tv.y * sW[2][k+1] + tv.z * sW[2][k+2] + tv.w * sW[2][k+3];
            a3 += tv.x * sW[3][k] + tv.y * sW[3][k+1] + tv.z * sW[3][k+2] + tv.w * sW[3][k+3];
            a4 += tv.x * sW[4][k] + tv.y * sW[4][k+1] + tv.z * sW[4][k+2] + tv.w * sW[4][k+3];
        }
        size_t rb = (size_t)b * R5;
        float ra  = rPart[rb + 0 * SZ + c] + a0;
        float ri  = rPart[rb + 1 * SZ + c] + a1;
        float rf1 = rPart[rb + 2 * SZ + c] + a2;
        float rf2 = rPart[rb + 3 * SZ + c] + a3;
        float ro  = rPart[rb + 4 * SZ + c] + a4;
        int i1 = s1src[t * B_ + b], i2 = s2src[t * B_ + b];
        float s1c = (i1 >= 0) ? tokens[((size_t)b * NS + i1) * 600 + SZ + c]
                              : stack [((size_t)b * NS + sp - 1) * 600 + SZ + c];
        float s2c = (i2 >= 0) ? tokens[((size_t)b * NS + i2) * 600 + SZ + c]
                              : stack [((size_t)b * NS + sp - 2) * 600 + SZ + c];
        float rc = tanhf(ra) * sigf(ri) + sigf(rf1) * s2c + sigf(rf2) * s1c;
        float rh = sigf(ro) * tanhf(rc);
        float* dst = stack + ((size_t)b * NS + sp - 2) * 600;
        dst[c]      = rh;
        dst[SZ + c] = rc;
    }
}

// ---------------------------------------------------------------------------
__global__ void kFinal(const float* __restrict__ tokens, const float* __restrict__ stack,
                       const int* __restrict__ finSrc, const int* __restrict__ sptrA,
                       float* __restrict__ out)
{
    int b  = blockIdx.x;
    int fs = finSrc[b];
    int sp = sptrA[TT * B_ + b];
    int slot = max(sp - 1, 0);
    const float* src = (fs >= 0) ? tokens + ((size_t)b * NS + fs) * 600
                                 : stack  + ((size_t)b * NS + slot) * 600;
    for (int i = threadIdx.x; i < 600; i += blockDim.x)
        out[(size_t)b * 600 + i] = src[i];
}

__global__ void kNll(const float* __restrict__ nll_row, float* __restrict__ out)
{
    __shared__ float sbuf[512];
    int tid = threadIdx.x;
    sbuf[tid] = nll_row[tid];
    __syncthreads();
    for (int s = 256; s > 0; s >>= 1) {
        if (tid < s) sbuf[tid] += sbuf[tid + s];
        __syncthreads();
    }
    if (tid == 0) out[(size_t)B_ * 600] = sbuf[0] / (float)(TT * B_);
}

// ---------------------------------------------------------------------------
extern "C" void kernel_launch(void* const* d_in, const int* in_sizes, int n_in,
                              void* d_out, int out_size, void* d_ws, size_t ws_size,
                              hipStream_t stream)
{
    const float* tokens = (const float*)d_in[0];
    const float* Wb   = (const float*)d_in[1];
    const float* Ws1  = (const float*)d_in[2];
    const float* Ws2  = (const float*)d_in[3];
    const float* W_ih = (const float*)d_in[4];
    const float* W_hh = (const float*)d_in[5];
    const float* Wt   = (const float*)d_in[6];
    const float* bt   = (const float*)d_in[7];
    const float* WL   = (const float*)d_in[8];
    const float* WR   = (const float*)d_in[9];
    const float* Wtr  = (const float*)d_in[10];
    const float* bL   = (const float*)d_in[11];
    const int* trans  = (const int*)d_in[12];
    float* out = (float*)d_out;

    char* p = (char*)d_ws;
    float* stack  = (float*)p;  p += (size_t)B_ * NS * 600 * 4;   // 157,286,400
    float* xBuf   = (float*)p;  p += (size_t)B_ * G4 * 4;         //     524,288
    float* rPart  = (float*)p;  p += (size_t)B_ * R5 * 4;         //   3,072,000
    float* th     = (float*)p;  p += (size_t)B_ * TS * 4;         //     131,072
    float* tc     = (float*)p;  p += (size_t)B_ * TS * 4;         //     131,072
    float* nllrow = (float*)p;  p += (size_t)B_ * 4;              //       2,048
    int* sptrA    = (int*)p;    p += (size_t)(TT + 1) * B_ * 4;   //     524,288
    int* bptrA    = (int*)p;    p += (size_t)TT * B_ * 4;         //     522,240
    int* s1src    = (int*)p;    p += (size_t)TT * B_ * 4;         //     522,240
    int* s2src    = (int*)p;    p += (size_t)TT * B_ * 4;         //     522,240
    int* redList  = (int*)p;    p += (size_t)TT * B_ * 4;         //     522,240
    int* finSrc   = (int*)p;    p += (size_t)B_ * 4;              //       2,048
    int* nredA    = (int*)p;    p += 256 * 4;                     //       1,024
    // total ~163.8 MB

    kZero<<<1, 256, 0, stream>>>(nredA);
    kSched<<<2, 256, 0, stream>>>(trans, sptrA, bptrA, s1src, s2src, finSrc,
                                  redList, nredA, th, tc, nllrow);
    for (int t = 0; t < TT; ++t) {
        kStep1<<<512, 512, 0, stream>>>(tokens, Wb, Ws1, Ws2, WL, WR, bL, stack,
                                        xBuf, rPart, sptrA, bptrA, s1src, s2src,
                                        redList, nredA, t);
        kStep2<<<64, 512, 0, stream>>>(W_ih, W_hh, Wt, bt, trans, xBuf, th, tc,
                                       nllrow, t);
        kStep3<<<300, 256, 0, stream>>>(tokens, Wtr, th, rPart, stack, sptrA,
                                        s1src, s2src, redList, nredA, t);
    }
    kFinal<<<512, 128, 0, stream>>>(tokens, stack, finSrc, sptrA, out);
    kNll<<<1, 512, 0, stream>>>(nllrow, out);
}